// Round 2
// baseline (298.491 us; speedup 1.0000x reference)
//
#include <hip/hip_runtime.h>
#include <hip/hip_bf16.h>
#include <stdint.h>

#define BB 2
#define SS 2048
#define DMM 2048
#define HH 16
#define DHH 128

typedef unsigned short u16;
typedef __attribute__((ext_vector_type(8))) short bf16x8;
typedef __attribute__((ext_vector_type(8))) unsigned short u16x8;
typedef __attribute__((ext_vector_type(4))) float f32x4;

#define WAITV(N) asm volatile("s_waitcnt vmcnt(" #N ")" ::: "memory")
#define WAITLGKM0 asm volatile("s_waitcnt lgkmcnt(0)" ::: "memory")

__device__ __forceinline__ u16 f2bf(float f) {
  union { float f; uint32_t u; } v; v.f = f;
  return (u16)((v.u + 0x7FFFu + ((v.u >> 16) & 1u)) >> 16);  // RNE
}

__device__ __forceinline__ void stage16(const void* g, void* l) {
  __builtin_amdgcn_global_load_lds(
      (const __attribute__((address_space(1))) void*)g,
      (__attribute__((address_space(3))) void*)l, 16, 0, 0);
}

// ---------------- f32 -> bf16 convert, 8 elems/thread ----------------
__global__ void cvt_bf16_k(const float* __restrict__ in, u16* __restrict__ out) {
  size_t i = (size_t)blockIdx.x * blockDim.x + threadIdx.x;
  const float4* p = (const float4*)in + i * 2;
  float4 a = p[0], b = p[1];
  u16x8 v;
  v[0] = f2bf(a.x); v[1] = f2bf(a.y); v[2] = f2bf(a.z); v[3] = f2bf(a.w);
  v[4] = f2bf(b.x); v[5] = f2bf(b.y); v[6] = f2bf(b.z); v[7] = f2bf(b.w);
  *((u16x8*)out + i) = v;
}

// ================= 256x256-tile 8-phase GEMM (QKV projection) =================
// C = A[M][K] * B[N][K]^T, fused epilogue: +bias, per-head rope (fc indexed by
// HEAD per reference quirk), scatter Q (scaled) / K [bh][s][128] / V^T [bh][128][s].
// 512 thr = 8 waves (4M x 2N), per-wave 64 rows x 128 cols. BK=64, dbuf LDS 128KB.
// Phase schedule (race-free by construction):
//   q0: ds af0(4)+bf0(8); stage (t+1).A1; bar; lgkm0; MFMA Q(0,0); bar
//   q1: ds af1(4);        stage (t+1).B1; bar; lgkm0; MFMA Q(1,0); bar
//   q2: ds bf1(8);        stage (t+2).A0; bar; lgkm0; MFMA Q(1,1); bar
//   q3: -;                stage (t+2).B0; bar; lgkm0; MFMA Q(0,1); vmcnt(4); bar
// A-region reads end q1 (A0 overwrite issued q2 OK); B-region reads end q2
// (B0 overwrite issued q3 OK) -- all ordered by the lgkm0-before-2nd-barrier.
// vmcnt(4) leaves {(t+2).A0,B0} in flight across the tile boundary (T4).
__global__ __launch_bounds__(512, 2)
void gemm_qkv8_k(const u16* __restrict__ A, const u16* __restrict__ Bm,
                 const float* __restrict__ bias,
                 const float* __restrict__ fcr, const float* __restrict__ fci,
                 u16* __restrict__ Qo, u16* __restrict__ Ko, u16* __restrict__ Vto,
                 int Kdim)
{
  const int tid = threadIdx.x;
  const int lane = tid & 63, w = tid >> 6, g = lane >> 4, c = lane & 15;
  const int wm = w >> 1, wn = w & 1;

  // XCD-aware swizzle (nwg = 384, %8 == 0)
  const int nwg = gridDim.x * gridDim.y;
  int flat = blockIdx.y * gridDim.x + blockIdx.x;
  flat = (flat & 7) * (nwg >> 3) + (flat >> 3);
  const int bn = flat % gridDim.x;
  const int bm = flat / gridDim.x;

  __shared__ __align__(16) u16 As[2][256 * 64];
  __shared__ __align__(16) u16 Bs[2][256 * 64];

  f32x4 acc[4][8] = {};

  const long K2 = (long)Kdim * 2;
  const char* Abase = (const char*)A + ((long)bm * 256) * K2;
  const char* Bbase = (const char*)Bm + ((long)bn * 256) * K2;
  const int nt = Kdim >> 6;

  // stage one 128x64 half-tile (2 x global_load_lds dwordx4 per thread),
  // linear LDS dest + inverse-swizzled global source (rule #21)
  auto stage_half = [&](const char* gb, int kb, u16* region, int halfbase) {
    #pragma unroll
    for (int i = 0; i < 2; ++i) {
      int off = halfbase + i * 8192 + tid * 16;
      int r = off >> 7, cb2 = off & 127;
      int cbs = cb2 ^ ((r & 7) << 4);
      stage16(gb + (long)r * K2 + kb * 2 + cbs, (char*)region + off);
    }
  };
  auto ldfrag = [&](const u16* region, int r, int cb) -> bf16x8 {
    int ab = (r << 7) + (cb ^ ((r & 7) << 4));
    return *(const bf16x8*)((const char*)region + ab);
  };

  // prologue: t0.{A0,B0,A1,B1}, t1.{A0,B0}; vmcnt(4) -> t0 fully staged
  stage_half(Abase, 0, As[0], 0);
  stage_half(Bbase, 0, Bs[0], 0);
  stage_half(Abase, 0, As[0], 16384);
  stage_half(Bbase, 0, Bs[0], 16384);
  stage_half(Abase, 64, As[1], 0);
  stage_half(Bbase, 64, Bs[1], 0);
  WAITV(4);
  __builtin_amdgcn_s_barrier();

  for (int t = 0; t < nt; ++t) {
    const int cur = t & 1;
    const int kb1 = (t + 1) << 6, kb2 = (t + 2) << 6;
    bf16x8 af0[2][2], af1[2][2], bf0[2][4], bf1[2][4];

    // ---- q0: af0 + bf0; stage (t+1).A1; MFMA Q(0,0) ----
    #pragma unroll
    for (int kc = 0; kc < 2; ++kc) {
      #pragma unroll
      for (int m = 0; m < 2; ++m)
        af0[kc][m] = ldfrag(As[cur], wm * 64 + m * 16 + c, kc * 64 + g * 16);
      #pragma unroll
      for (int n = 0; n < 4; ++n)
        bf0[kc][n] = ldfrag(Bs[cur], wn * 128 + n * 16 + c, kc * 64 + g * 16);
    }
    if (t + 1 < nt) stage_half(Abase, kb1, As[cur ^ 1], 16384);
    __builtin_amdgcn_s_barrier();
    WAITLGKM0;
    __builtin_amdgcn_s_setprio(1);
    #pragma unroll
    for (int kc = 0; kc < 2; ++kc)
      #pragma unroll
      for (int m = 0; m < 2; ++m)
        #pragma unroll
        for (int n = 0; n < 4; ++n)
          acc[m][n] = __builtin_amdgcn_mfma_f32_16x16x32_bf16(af0[kc][m], bf0[kc][n], acc[m][n], 0, 0, 0);
    __builtin_amdgcn_s_setprio(0);
    __builtin_amdgcn_s_barrier();

    // ---- q1: af1; stage (t+1).B1; MFMA Q(1,0) ----
    #pragma unroll
    for (int kc = 0; kc < 2; ++kc)
      #pragma unroll
      for (int m = 0; m < 2; ++m)
        af1[kc][m] = ldfrag(As[cur], wm * 64 + 32 + m * 16 + c, kc * 64 + g * 16);
    if (t + 1 < nt) stage_half(Bbase, kb1, Bs[cur ^ 1], 16384);
    __builtin_amdgcn_s_barrier();
    WAITLGKM0;
    __builtin_amdgcn_s_setprio(1);
    #pragma unroll
    for (int kc = 0; kc < 2; ++kc)
      #pragma unroll
      for (int m = 0; m < 2; ++m)
        #pragma unroll
        for (int n = 0; n < 4; ++n)
          acc[2 + m][n] = __builtin_amdgcn_mfma_f32_16x16x32_bf16(af1[kc][m], bf0[kc][n], acc[2 + m][n], 0, 0, 0);
    __builtin_amdgcn_s_setprio(0);
    __builtin_amdgcn_s_barrier();

    // ---- q2: bf1; stage (t+2).A0; MFMA Q(1,1) ----
    #pragma unroll
    for (int kc = 0; kc < 2; ++kc)
      #pragma unroll
      for (int n = 0; n < 4; ++n)
        bf1[kc][n] = ldfrag(Bs[cur], wn * 128 + 64 + n * 16 + c, kc * 64 + g * 16);
    if (t + 2 < nt) stage_half(Abase, kb2, As[cur], 0);
    __builtin_amdgcn_s_barrier();
    WAITLGKM0;
    __builtin_amdgcn_s_setprio(1);
    #pragma unroll
    for (int kc = 0; kc < 2; ++kc)
      #pragma unroll
      for (int m = 0; m < 2; ++m)
        #pragma unroll
        for (int n = 0; n < 4; ++n)
          acc[2 + m][4 + n] = __builtin_amdgcn_mfma_f32_16x16x32_bf16(af1[kc][m], bf1[kc][n], acc[2 + m][4 + n], 0, 0, 0);
    __builtin_amdgcn_s_setprio(0);
    __builtin_amdgcn_s_barrier();

    // ---- q3: stage (t+2).B0; MFMA Q(0,1); counted vmcnt ----
    if (t + 2 < nt) stage_half(Bbase, kb2, Bs[cur], 0);
    __builtin_amdgcn_s_barrier();
    WAITLGKM0;
    __builtin_amdgcn_s_setprio(1);
    #pragma unroll
    for (int kc = 0; kc < 2; ++kc)
      #pragma unroll
      for (int m = 0; m < 2; ++m)
        #pragma unroll
        for (int n = 0; n < 4; ++n)
          acc[m][4 + n] = __builtin_amdgcn_mfma_f32_16x16x32_bf16(af0[kc][m], bf1[kc][n], acc[m][4 + n], 0, 0, 0);
    __builtin_amdgcn_s_setprio(0);
    if (t < nt - 2) { WAITV(4); }
    else if (t == nt - 2) { WAITV(0); }
    __builtin_amdgcn_s_barrier();
  }

  // ---- epilogue: bias + rope + scatter ----
  const int sec = bn * 2 + wn;          // 0..47 (16 Q, 16 K, 16 V sections)
  const int kind = sec >> 4, h = sec & 15;
  const int rowb = bm * 256 + wm * 64;
  if (kind < 2) {
    const float scale = (kind == 0) ? 0.08838834764831845f : 1.0f;  // DH^-0.5 in Q
    u16* O = (kind == 0) ? Qo : Ko;
    #pragma unroll
    for (int nf = 0; nf < 4; ++nf) {
      int d = nf * 16 + c;
      float fr = fcr[h * 64 + d], fi = fci[h * 64 + d];  // per-HEAD angle (ref quirk)
      float bre = bias[sec * 128 + d], bim = bias[sec * 128 + 64 + d];
      #pragma unroll
      for (int mf = 0; mf < 4; ++mf)
        #pragma unroll
        for (int j = 0; j < 4; ++j) {
          int row = rowb + mf * 16 + g * 4 + j;
          int s = row & (SS - 1), b = row >> 11;
          float re = acc[mf][nf][j] + bre;
          float im = acc[mf][nf + 4][j] + bim;
          long base = (((long)(b * HH + h)) * SS + s) * DHH;
          O[base + d]      = f2bf((re * fr - im * fi) * scale);
          O[base + 64 + d] = f2bf((re * fi + im * fr) * scale);
        }
    }
  } else {
    #pragma unroll
    for (int nf = 0; nf < 8; ++nf) {
      int d = nf * 16 + c;
      float bv = bias[sec * 128 + d];
      #pragma unroll
      for (int mf = 0; mf < 4; ++mf)
        #pragma unroll
        for (int j = 0; j < 4; ++j) {
          int row = rowb + mf * 16 + g * 4 + j;
          int s = row & (SS - 1), b = row >> 11;
          Vto[(((long)(b * HH + h)) * DHH + d) * SS + s] = f2bf(acc[mf][nf][j] + bv);
        }
    }
  }
}

// ---------------- 128x128-tile GEMM (unchanged, used for out-proj) ----------------
template<int MODE>
__global__ __launch_bounds__(256)
void gemm_bt_k(const u16* __restrict__ A, const u16* __restrict__ Bm,
               const float* __restrict__ bias,
               const float* __restrict__ fcr, const float* __restrict__ fci,
               u16* __restrict__ Qo, u16* __restrict__ Ko, u16* __restrict__ Vto,
               float* __restrict__ Fo,
               int Mdim, int Ndim, int Kdim)
{
  const int tid = threadIdx.x;
  const int lane = tid & 63, w = tid >> 6, g = lane >> 4, c = lane & 15;
  const int bn = blockIdx.x, bm = blockIdx.y;

  __shared__ __align__(16) u16 As[128 * 64];
  __shared__ __align__(16) u16 Bs[128 * 64];

  constexpr int MF = (MODE == 0) ? 2 : 4;
  constexpr int NF = (MODE == 0) ? 8 : 4;
  const int wrow = (MODE == 0) ? w * 32 : (w >> 1) * 64;
  const int wcol = (MODE == 0) ? 0 : (w & 1) * 64;

  f32x4 acc[MF][NF] = {};

  const char* Abase = (const char*)A + ((long)bm * 128) * Kdim * 2;
  const char* Bbase = (const char*)Bm + ((long)bn * 128) * Kdim * 2;
  const int wub = w * 1024;

  for (int kb = 0; kb < Kdim; kb += 64) {
    #pragma unroll
    for (int i = 0; i < 4; ++i) {
      int ob = i * 4096 + wub;
      int o = ob + (lane << 4);
      int r = o >> 7, cb = o & 127;
      int cbs = cb ^ ((r & 7) << 4);
      stage16(Abase + ((long)r * Kdim + kb) * 2 + cbs, (char*)As + ob);
    }
    #pragma unroll
    for (int i = 0; i < 4; ++i) {
      int ob = i * 4096 + wub;
      int o = ob + (lane << 4);
      int r = o >> 7, cb = o & 127;
      int cbs = cb ^ ((r & 7) << 4);
      stage16(Bbase + ((long)r * Kdim + kb) * 2 + cbs, (char*)Bs + ob);
    }
    __syncthreads();
    #pragma unroll
    for (int kc = 0; kc < 2; ++kc) {
      bf16x8 af[MF], bfr[NF];
      #pragma unroll
      for (int mf = 0; mf < MF; ++mf) {
        int r = wrow + mf * 16 + c;
        int ab = (r << 7) + kc * 64 + (g << 4);
        ab ^= (r & 7) << 4;
        af[mf] = *(const bf16x8*)((const char*)As + ab);
      }
      #pragma unroll
      for (int nf = 0; nf < NF; ++nf) {
        int r = wcol + nf * 16 + c;
        int ab = (r << 7) + kc * 64 + (g << 4);
        ab ^= (r & 7) << 4;
        bfr[nf] = *(const bf16x8*)((const char*)Bs + ab);
      }
      #pragma unroll
      for (int mf = 0; mf < MF; ++mf)
        #pragma unroll
        for (int nf = 0; nf < NF; ++nf)
          acc[mf][nf] = __builtin_amdgcn_mfma_f32_16x16x32_bf16(af[mf], bfr[nf], acc[mf][nf], 0, 0, 0);
    }
    __syncthreads();
  }

  if constexpr (MODE == 1) {
    #pragma unroll
    for (int mf = 0; mf < MF; ++mf)
      #pragma unroll
      for (int nf = 0; nf < NF; ++nf) {
        int col = bn * 128 + wcol + nf * 16 + c;
        float bv = bias[col];
        #pragma unroll
        for (int j = 0; j < 4; ++j) {
          int row = bm * 128 + wrow + mf * 16 + g * 4 + j;
          Fo[(long)row * Ndim + col] = acc[mf][nf][j] + bv;
        }
      }
  }
}

// ---------------- causal flash attention (unchanged) ----------------
__global__ __launch_bounds__(256)
void attn_k(const u16* __restrict__ Q, const u16* __restrict__ K,
            const u16* __restrict__ Vt, u16* __restrict__ Ao)
{
  const int tid = threadIdx.x;
  const int lane = tid & 63, w = tid >> 6, g = lane >> 4, c = lane & 15;
  const int bh = blockIdx.x;
  const int qt = (int)(gridDim.y - 1 - blockIdx.y);
  const int b = bh >> 4, h = bh & 15;
  const int qbase = qt * 64;

  __shared__ __align__(16) u16 Ks[64 * 128];
  __shared__ __align__(16) u16 Vts[128 * 64];
  __shared__ __align__(16) u16 Ps[4][16 * 64];

  const long head = (long)bh * SS * DHH;

  bf16x8 qf[4];
  {
    const u16* qp = Q + head + (long)(qbase + w * 16 + c) * DHH + g * 8;
    #pragma unroll
    for (int kc = 0; kc < 4; ++kc) qf[kc] = *(const bf16x8*)(qp + kc * 32);
  }

  f32x4 o[8] = {};
  float m[4], l[4];
  #pragma unroll
  for (int j = 0; j < 4; ++j) { m[j] = -INFINITY; l[j] = 0.f; }

  const int wub = w * 1024;
  for (int t = 0; t <= qt; ++t) {
    const int kvbase = t * 64;
    #pragma unroll
    for (int i = 0; i < 4; ++i) {
      int ob = i * 4096 + wub;
      int o_ = ob + (lane << 4);
      int r = o_ >> 8, cb = o_ & 255;
      int cbs = cb ^ ((r & 7) << 4);
      stage16((const char*)(K + head) + (long)(kvbase + r) * 256 + cbs, (char*)Ks + ob);
    }
    #pragma unroll
    for (int i = 0; i < 4; ++i) {
      int ob = i * 4096 + wub;
      int o_ = ob + (lane << 4);
      int r = o_ >> 7, cb = o_ & 127;
      int cbs = cb ^ ((r & 7) << 4);
      stage16((const char*)(Vt + head) + (long)r * (SS * 2) + kvbase * 2 + cbs, (char*)Vts + ob);
    }
    __syncthreads();

    f32x4 sf[4];
    #pragma unroll
    for (int nf = 0; nf < 4; ++nf) {
      f32x4 s = {0.f, 0.f, 0.f, 0.f};
      #pragma unroll
      for (int kc = 0; kc < 4; ++kc) {
        int r = nf * 16 + c;
        int ab = (r << 8) + kc * 64 + (g << 4);
        ab ^= (r & 7) << 4;
        bf16x8 kf = *(const bf16x8*)((const char*)Ks + ab);
        s = __builtin_amdgcn_mfma_f32_16x16x32_bf16(qf[kc], kf, s, 0, 0, 0);
      }
      sf[nf] = s;
    }

    if (t == qt) {
      #pragma unroll
      for (int nf = 0; nf < 4; ++nf)
        #pragma unroll
        for (int j = 0; j < 4; ++j)
          if (nf * 16 + c > w * 16 + g * 4 + j) sf[nf][j] = -INFINITY;
    }

    float mn[4], cf[4], rs[4];
    #pragma unroll
    for (int j = 0; j < 4; ++j) {
      float v = fmaxf(fmaxf(sf[0][j], sf[1][j]), fmaxf(sf[2][j], sf[3][j]));
      v = fmaxf(v, __shfl_xor(v, 1));
      v = fmaxf(v, __shfl_xor(v, 2));
      v = fmaxf(v, __shfl_xor(v, 4));
      v = fmaxf(v, __shfl_xor(v, 8));
      mn[j] = fmaxf(m[j], v);
      cf[j] = exp2f((m[j] - mn[j]) * 1.4426950408889634f);
      m[j] = mn[j];
      rs[j] = 0.f;
    }
    #pragma unroll
    for (int nf = 0; nf < 4; ++nf)
      #pragma unroll
      for (int j = 0; j < 4; ++j) {
        float p = exp2f((sf[nf][j] - mn[j]) * 1.4426950408889634f);
        sf[nf][j] = p;
        rs[j] += p;
      }
    #pragma unroll
    for (int j = 0; j < 4; ++j) {
      float v = rs[j];
      v += __shfl_xor(v, 1); v += __shfl_xor(v, 2);
      v += __shfl_xor(v, 4); v += __shfl_xor(v, 8);
      l[j] = l[j] * cf[j] + v;
    }
    #pragma unroll
    for (int nf = 0; nf < 8; ++nf)
      #pragma unroll
      for (int j = 0; j < 4; ++j)
        o[nf][j] *= cf[j];

    #pragma unroll
    for (int nf = 0; nf < 4; ++nf)
      #pragma unroll
      for (int j = 0; j < 4; ++j) {
        int pr = g * 4 + j;
        int ab = (pr << 7) + (nf * 16 + c) * 2;
        ab ^= (pr & 7) << 4;
        *(u16*)((char*)Ps[w] + ab) = f2bf(sf[nf][j]);
      }

    bf16x8 pf[2];
    #pragma unroll
    for (int kc = 0; kc < 2; ++kc) {
      int ab = (c << 7) + kc * 64 + (g << 4);
      ab ^= (c & 7) << 4;
      pf[kc] = *(const bf16x8*)((const char*)Ps[w] + ab);
    }
    #pragma unroll
    for (int nf = 0; nf < 8; ++nf) {
      #pragma unroll
      for (int kc = 0; kc < 2; ++kc) {
        int r = nf * 16 + c;
        int ab = (r << 7) + kc * 64 + (g << 4);
        ab ^= (r & 7) << 4;
        bf16x8 vf = *(const bf16x8*)((const char*)Vts + ab);
        o[nf] = __builtin_amdgcn_mfma_f32_16x16x32_bf16(pf[kc], vf, o[nf], 0, 0, 0);
      }
    }
    __syncthreads();
  }

  #pragma unroll
  for (int j = 0; j < 4; ++j) {
    float inv = 1.0f / l[j];
    int row = qbase + w * 16 + g * 4 + j;
    long ob = ((long)(b * SS + row)) * DMM + h * DHH;
    #pragma unroll
    for (int nf = 0; nf < 8; ++nf)
      Ao[ob + nf * 16 + c] = f2bf(o[nf][j] * inv);
  }
}

extern "C" void kernel_launch(void* const* d_in, const int* in_sizes, int n_in,
                              void* d_out, int out_size, void* d_ws, size_t ws_size,
                              hipStream_t stream) {
  const float* x     = (const float*)d_in[0];
  const float* w_qkv = (const float*)d_in[1];
  const float* b_qkv = (const float*)d_in[2];
  const float* w_out = (const float*)d_in[3];
  const float* b_out = (const float*)d_in[4];
  const float* fcr   = (const float*)d_in[5];
  const float* fci   = (const float*)d_in[6];
  float* outp = (float*)d_out;

  char* ws = (char*)d_ws;               // needs 96 MB
  u16* xb  = (u16*)(ws + 0);            // 16MB x bf16 [4096][2048]
  u16* wqb = (u16*)(ws + (16L << 20));  // 24MB w_qkv bf16 [6144][2048]
  u16* wob = (u16*)(ws + (40L << 20));  // 8MB  w_out bf16 [2048][2048]
  u16* Qb  = (u16*)(ws + (48L << 20));  // 16MB [bh][s][128] (scaled+roped)
  u16* Kb  = (u16*)(ws + (64L << 20));  // 16MB [bh][s][128] (roped)
  u16* Vtb = (u16*)(ws + (80L << 20));  // 16MB [bh][128][s]
  u16* attno = xb;                      // alias: xb dead after GEMM1

  cvt_bf16_k<<<4096, 256, 0, stream>>>(x, xb);
  cvt_bf16_k<<<6144, 256, 0, stream>>>(w_qkv, wqb);
  cvt_bf16_k<<<2048, 256, 0, stream>>>(w_out, wob);

  gemm_qkv8_k<<<dim3(24, 16), 512, 0, stream>>>(
      xb, wqb, b_qkv, fcr, fci, Qb, Kb, Vtb, 2048);

  attn_k<<<dim3(32, 32), 256, 0, stream>>>(Qb, Kb, Vtb, attno);

  gemm_bt_k<1><<<dim3(16, 32), 256, 0, stream>>>(
      attno, wob, b_out, nullptr, nullptr, nullptr, nullptr, nullptr, outp,
      4096, 2048, 2048);
}

// Round 3
// 290.144 us; speedup vs baseline: 1.0288x; 1.0288x over previous
//
#include <hip/hip_runtime.h>
#include <hip/hip_bf16.h>
#include <stdint.h>

#define BB 2
#define SS 2048
#define DMM 2048
#define HH 16
#define DHH 128

typedef unsigned short u16;
typedef __attribute__((ext_vector_type(8))) short bf16x8;
typedef __attribute__((ext_vector_type(8))) unsigned short u16x8;
typedef __attribute__((ext_vector_type(4))) float f32x4;

#define WAITV(N) asm volatile("s_waitcnt vmcnt(" #N ")" ::: "memory")
#define WAITLGKM0 asm volatile("s_waitcnt lgkmcnt(0)" ::: "memory")
#define SCHEDBAR __builtin_amdgcn_sched_barrier(0)

__device__ __forceinline__ u16 f2bf(float f) {
  union { float f; uint32_t u; } v; v.f = f;
  return (u16)((v.u + 0x7FFFu + ((v.u >> 16) & 1u)) >> 16);  // RNE
}

__device__ __forceinline__ void stage16(const void* g, void* l) {
  __builtin_amdgcn_global_load_lds(
      (const __attribute__((address_space(1))) void*)g,
      (__attribute__((address_space(3))) void*)l, 16, 0, 0);
}

// ---------------- f32 -> bf16 convert, 8 elems/thread ----------------
__global__ void cvt_bf16_k(const float* __restrict__ in, u16* __restrict__ out) {
  size_t i = (size_t)blockIdx.x * blockDim.x + threadIdx.x;
  const float4* p = (const float4*)in + i * 2;
  float4 a = p[0], b = p[1];
  u16x8 v;
  v[0] = f2bf(a.x); v[1] = f2bf(a.y); v[2] = f2bf(a.z); v[3] = f2bf(a.w);
  v[4] = f2bf(b.x); v[5] = f2bf(b.y); v[6] = f2bf(b.z); v[7] = f2bf(b.w);
  *((u16x8*)out + i) = v;
}

// ================= 256x256-tile 8-phase GEMM (QKV projection) =================
// Deep-pipelined per m201/T3+T4. LDS rows are PERMUTED so each phase's
// release-set is a contiguous 16KB half:
//   A half0 (LDS rows 0-127)  = matrix rows wm*64+{0..31}  (read by af0, q0)
//   A half1 (LDS rows 128-255)= matrix rows wm*64+{32..63} (read by af1, q1)
//   B half0                   = matrix rows wn*128+{0..63} (read by bf0, q0)
//   B half1                   = matrix rows wn*128+{64..127}(read by bf1, q2)
// Stage calendar during tile T (one 16KB half per phase, 2 loads each):
//   q0: (T+1).B1 -> Bs[oth]   (region last read at (T-1).q2, 2 phases prior)
//   q1: (T+2).A0 -> As[cur]   (af0 of T drained at q0)
//   q2: (T+2).A1 -> As[cur]   (af1 drained at q1)
//   q3: (T+2).B0 -> Bs[cur]   (bf0 drained at q0)
// Waits: WAITV(10) end-q1 retires (T+1).B1 (5-phase cover);
//        WAITV(8)  end-q3 retires (T+2).{A0,A1,B0} (6.5-8.5 phase cover).
// Steady-state outstanding after q3-wait: {(T+1).B1,(T+2).A0,A1,B0} = 8 loads.
__global__ __launch_bounds__(512, 2)
void gemm_qkv8_k(const u16* __restrict__ A, const u16* __restrict__ Bm,
                 const float* __restrict__ bias,
                 const float* __restrict__ fcr, const float* __restrict__ fci,
                 u16* __restrict__ Qo, u16* __restrict__ Ko, u16* __restrict__ Vto,
                 int Kdim)
{
  const int tid = threadIdx.x;
  const int lane = tid & 63, w = tid >> 6, g = lane >> 4, c = lane & 15;
  const int wm = w >> 1, wn = w & 1;

  // XCD chunking, bm-fast: each XCD owns 3 bn-panels (3MB B -> L2-resident),
  // streams whole A from L3. nwg=384, %8==0.
  const int nwg = gridDim.x * gridDim.y;
  int flat = blockIdx.y * gridDim.x + blockIdx.x;
  flat = (flat & 7) * (nwg >> 3) + (flat >> 3);
  const int bm = flat % gridDim.y;
  const int bn = flat / gridDim.y;

  __shared__ __align__(16) u16 As[2][256 * 64];
  __shared__ __align__(16) u16 Bs[2][256 * 64];

  f32x4 acc[4][8] = {};

  const long K2 = (long)Kdim * 2;
  const char* Abase = (const char*)A + ((long)bm * 256) * K2;
  const char* Bbase = (const char*)Bm + ((long)bn * 256) * K2;
  const int nt = Kdim >> 6;

  // stage one permuted 128-LDS-row half (16KB, 2 x global_load_lds_dwordx4/thr);
  // linear LDS dest + inverse-swizzled inverse-permuted global source.
  auto stageA = [&](int kb, u16* buf, int half) {
    #pragma unroll
    for (int i = 0; i < 2; ++i) {
      int off = half * 16384 + i * 8192 + tid * 16;
      int rl = off >> 7, cb2 = off & 127;
      int cbs = cb2 ^ ((rl & 7) << 4);
      int rm = ((rl >> 5) & 3) * 64 + half * 32 + (rl & 31);
      stage16(Abase + (long)rm * K2 + kb * 2 + cbs, (char*)buf + off);
    }
  };
  auto stageB = [&](int kb, u16* buf, int half) {
    #pragma unroll
    for (int i = 0; i < 2; ++i) {
      int off = half * 16384 + i * 8192 + tid * 16;
      int rl = off >> 7, cb2 = off & 127;
      int cbs = cb2 ^ ((rl & 7) << 4);
      int rm = ((rl >> 6) & 1) * 128 + half * 64 + (rl & 63);
      stage16(Bbase + (long)rm * K2 + kb * 2 + cbs, (char*)buf + off);
    }
  };
  auto ldr = [&](const u16* buf, int rl, int cb) -> bf16x8 {
    int ab = (rl << 7) + (cb ^ ((rl & 7) << 4));
    return *(const bf16x8*)((const char*)buf + ab);
  };

  // prologue: t0.{A0,A1,B0}, t0.B1, t1.{A0,A1,B0} = 14 loads; WAITV(8)
  // retires t0.{A0,A1,B0} -> exact steady state {t0.B1, t1.A0,A1,B0}.
  stageA(0, As[0], 0); stageA(0, As[0], 1); stageB(0, Bs[0], 0);
  stageB(0, Bs[0], 1);
  stageA(64, As[1], 0); stageA(64, As[1], 1); stageB(64, Bs[1], 0);
  WAITV(8);
  __builtin_amdgcn_s_barrier();

  for (int t = 0; t < nt; ++t) {
    const int cur = t & 1;
    u16* Ac = As[cur];
    u16* Bc = Bs[cur];
    const int kb1 = (t + 1) << 6, kb2 = (t + 2) << 6;
    bf16x8 af0[2][2], af1[2][2], bf0[2][4], bf1[2][4];

    // ---- q0: ds af0+bf0; stage (t+1).B1; MFMA Q(0,0) ----
    #pragma unroll
    for (int kc = 0; kc < 2; ++kc) {
      #pragma unroll
      for (int m = 0; m < 2; ++m)
        af0[kc][m] = ldr(Ac, wm * 32 + m * 16 + c, kc * 64 + g * 16);
      #pragma unroll
      for (int n = 0; n < 4; ++n)
        bf0[kc][n] = ldr(Bc, wn * 64 + n * 16 + c, kc * 64 + g * 16);
    }
    if (t + 1 < nt) stageB(kb1, Bs[cur ^ 1], 1);
    __builtin_amdgcn_s_barrier();
    WAITLGKM0; SCHEDBAR;
    __builtin_amdgcn_s_setprio(1);
    #pragma unroll
    for (int kc = 0; kc < 2; ++kc)
      #pragma unroll
      for (int m = 0; m < 2; ++m)
        #pragma unroll
        for (int n = 0; n < 4; ++n)
          acc[m][n] = __builtin_amdgcn_mfma_f32_16x16x32_bf16(af0[kc][m], bf0[kc][n], acc[m][n], 0, 0, 0);
    __builtin_amdgcn_s_setprio(0);
    __builtin_amdgcn_s_barrier();

    // ---- q1: ds af1; stage (t+2).A0; MFMA Q(1,0); WAITV(10) ----
    #pragma unroll
    for (int kc = 0; kc < 2; ++kc)
      #pragma unroll
      for (int m = 0; m < 2; ++m)
        af1[kc][m] = ldr(Ac, 128 + wm * 32 + m * 16 + c, kc * 64 + g * 16);
    if (t + 2 < nt) stageA(kb2, Ac, 0);
    __builtin_amdgcn_s_barrier();
    WAITLGKM0; SCHEDBAR;
    __builtin_amdgcn_s_setprio(1);
    #pragma unroll
    for (int kc = 0; kc < 2; ++kc)
      #pragma unroll
      for (int m = 0; m < 2; ++m)
        #pragma unroll
        for (int n = 0; n < 4; ++n)
          acc[2 + m][n] = __builtin_amdgcn_mfma_f32_16x16x32_bf16(af1[kc][m], bf0[kc][n], acc[2 + m][n], 0, 0, 0);
    __builtin_amdgcn_s_setprio(0);
    if (t < nt - 3) { WAITV(10); } else { WAITV(0); }
    __builtin_amdgcn_s_barrier();

    // ---- q2: ds bf1; stage (t+2).A1; MFMA Q(1,1) ----
    #pragma unroll
    for (int kc = 0; kc < 2; ++kc)
      #pragma unroll
      for (int n = 0; n < 4; ++n)
        bf1[kc][n] = ldr(Bc, 128 + wn * 64 + n * 16 + c, kc * 64 + g * 16);
    if (t + 2 < nt) stageA(kb2, Ac, 1);
    __builtin_amdgcn_s_barrier();
    WAITLGKM0; SCHEDBAR;
    __builtin_amdgcn_s_setprio(1);
    #pragma unroll
    for (int kc = 0; kc < 2; ++kc)
      #pragma unroll
      for (int m = 0; m < 2; ++m)
        #pragma unroll
        for (int n = 0; n < 4; ++n)
          acc[2 + m][4 + n] = __builtin_amdgcn_mfma_f32_16x16x32_bf16(af1[kc][m], bf1[kc][n], acc[2 + m][4 + n], 0, 0, 0);
    __builtin_amdgcn_s_setprio(0);
    __builtin_amdgcn_s_barrier();

    // ---- q3: stage (t+2).B0; MFMA Q(0,1); WAITV(8) ----
    if (t + 2 < nt) stageB(kb2, Bc, 0);
    __builtin_amdgcn_s_barrier();
    __builtin_amdgcn_s_setprio(1);
    #pragma unroll
    for (int kc = 0; kc < 2; ++kc)
      #pragma unroll
      for (int m = 0; m < 2; ++m)
        #pragma unroll
        for (int n = 0; n < 4; ++n)
          acc[m][4 + n] = __builtin_amdgcn_mfma_f32_16x16x32_bf16(af0[kc][m], bf1[kc][n], acc[m][4 + n], 0, 0, 0);
    __builtin_amdgcn_s_setprio(0);
    if (t < nt - 3) { WAITV(8); } else { WAITV(0); }
    __builtin_amdgcn_s_barrier();
  }

  // ---- epilogue: bias + rope + scatter ----
  const int sec = bn * 2 + wn;          // 0..47 (16 Q, 16 K, 16 V sections)
  const int kind = sec >> 4, h = sec & 15;
  const int rowb = bm * 256 + wm * 64;
  if (kind < 2) {
    const float scale = (kind == 0) ? 0.08838834764831845f : 1.0f;  // DH^-0.5 in Q
    u16* O = (kind == 0) ? Qo : Ko;
    #pragma unroll
    for (int nf = 0; nf < 4; ++nf) {
      int d = nf * 16 + c;
      float fr = fcr[h * 64 + d], fi = fci[h * 64 + d];  // per-HEAD angle (ref quirk)
      float bre = bias[sec * 128 + d], bim = bias[sec * 128 + 64 + d];
      #pragma unroll
      for (int mf = 0; mf < 4; ++mf)
        #pragma unroll
        for (int j = 0; j < 4; ++j) {
          int row = rowb + mf * 16 + g * 4 + j;
          int s = row & (SS - 1), b = row >> 11;
          float re = acc[mf][nf][j] + bre;
          float im = acc[mf][nf + 4][j] + bim;
          long base = (((long)(b * HH + h)) * SS + s) * DHH;
          O[base + d]      = f2bf((re * fr - im * fi) * scale);
          O[base + 64 + d] = f2bf((re * fi + im * fr) * scale);
        }
    }
  } else {
    #pragma unroll
    for (int nf = 0; nf < 8; ++nf) {
      int d = nf * 16 + c;
      float bv = bias[sec * 128 + d];
      #pragma unroll
      for (int mf = 0; mf < 4; ++mf)
        #pragma unroll
        for (int j = 0; j < 4; ++j) {
          int row = rowb + mf * 16 + g * 4 + j;
          int s = row & (SS - 1), b = row >> 11;
          Vto[(((long)(b * HH + h)) * DHH + d) * SS + s] = f2bf(acc[mf][nf][j] + bv);
        }
    }
  }
}

// ---------------- 128x128-tile GEMM (unchanged, used for out-proj) ----------------
template<int MODE>
__global__ __launch_bounds__(256)
void gemm_bt_k(const u16* __restrict__ A, const u16* __restrict__ Bm,
               const float* __restrict__ bias,
               float* __restrict__ Fo,
               int Ndim, int Kdim)
{
  const int tid = threadIdx.x;
  const int lane = tid & 63, w = tid >> 6, g = lane >> 4, c = lane & 15;
  const int bn = blockIdx.x, bm = blockIdx.y;

  __shared__ __align__(16) u16 As[128 * 64];
  __shared__ __align__(16) u16 Bs[128 * 64];

  constexpr int MF = 4;
  constexpr int NF = 4;
  const int wrow = (w >> 1) * 64;
  const int wcol = (w & 1) * 64;

  f32x4 acc[MF][NF] = {};

  const char* Abase = (const char*)A + ((long)bm * 128) * Kdim * 2;
  const char* Bbase = (const char*)Bm + ((long)bn * 128) * Kdim * 2;
  const int wub = w * 1024;

  for (int kb = 0; kb < Kdim; kb += 64) {
    #pragma unroll
    for (int i = 0; i < 4; ++i) {
      int ob = i * 4096 + wub;
      int o = ob + (lane << 4);
      int r = o >> 7, cb = o & 127;
      int cbs = cb ^ ((r & 7) << 4);
      stage16(Abase + ((long)r * Kdim + kb) * 2 + cbs, (char*)As + ob);
    }
    #pragma unroll
    for (int i = 0; i < 4; ++i) {
      int ob = i * 4096 + wub;
      int o = ob + (lane << 4);
      int r = o >> 7, cb = o & 127;
      int cbs = cb ^ ((r & 7) << 4);
      stage16(Bbase + ((long)r * Kdim + kb) * 2 + cbs, (char*)Bs + ob);
    }
    __syncthreads();
    #pragma unroll
    for (int kc = 0; kc < 2; ++kc) {
      bf16x8 af[MF], bfr[NF];
      #pragma unroll
      for (int mf = 0; mf < MF; ++mf) {
        int r = wrow + mf * 16 + c;
        int ab = (r << 7) + kc * 64 + (g << 4);
        ab ^= (r & 7) << 4;
        af[mf] = *(const bf16x8*)((const char*)As + ab);
      }
      #pragma unroll
      for (int nf = 0; nf < NF; ++nf) {
        int r = wcol + nf * 16 + c;
        int ab = (r << 7) + kc * 64 + (g << 4);
        ab ^= (r & 7) << 4;
        bfr[nf] = *(const bf16x8*)((const char*)Bs + ab);
      }
      #pragma unroll
      for (int mf = 0; mf < MF; ++mf)
        #pragma unroll
        for (int nf = 0; nf < NF; ++nf)
          acc[mf][nf] = __builtin_amdgcn_mfma_f32_16x16x32_bf16(af[mf], bfr[nf], acc[mf][nf], 0, 0, 0);
    }
    __syncthreads();
  }

  #pragma unroll
  for (int mf = 0; mf < MF; ++mf)
    #pragma unroll
    for (int nf = 0; nf < NF; ++nf) {
      int col = bn * 128 + wcol + nf * 16 + c;
      float bv = bias[col];
      #pragma unroll
      for (int j = 0; j < 4; ++j) {
        int row = bm * 128 + wrow + mf * 16 + g * 4 + j;
        Fo[(long)row * Ndim + col] = acc[mf][nf][j] + bv;
      }
    }
}

// ---------------- causal flash attention (unchanged) ----------------
__global__ __launch_bounds__(256)
void attn_k(const u16* __restrict__ Q, const u16* __restrict__ K,
            const u16* __restrict__ Vt, u16* __restrict__ Ao)
{
  const int tid = threadIdx.x;
  const int lane = tid & 63, w = tid >> 6, g = lane >> 4, c = lane & 15;
  const int bh = blockIdx.x;
  const int qt = (int)(gridDim.y - 1 - blockIdx.y);
  const int b = bh >> 4, h = bh & 15;
  const int qbase = qt * 64;

  __shared__ __align__(16) u16 Ks[64 * 128];
  __shared__ __align__(16) u16 Vts[128 * 64];
  __shared__ __align__(16) u16 Ps[4][16 * 64];

  const long head = (long)bh * SS * DHH;

  bf16x8 qf[4];
  {
    const u16* qp = Q + head + (long)(qbase + w * 16 + c) * DHH + g * 8;
    #pragma unroll
    for (int kc = 0; kc < 4; ++kc) qf[kc] = *(const bf16x8*)(qp + kc * 32);
  }

  f32x4 o[8] = {};
  float m[4], l[4];
  #pragma unroll
  for (int j = 0; j < 4; ++j) { m[j] = -INFINITY; l[j] = 0.f; }

  const int wub = w * 1024;
  for (int t = 0; t <= qt; ++t) {
    const int kvbase = t * 64;
    #pragma unroll
    for (int i = 0; i < 4; ++i) {
      int ob = i * 4096 + wub;
      int o_ = ob + (lane << 4);
      int r = o_ >> 8, cb = o_ & 255;
      int cbs = cb ^ ((r & 7) << 4);
      stage16((const char*)(K + head) + (long)(kvbase + r) * 256 + cbs, (char*)Ks + ob);
    }
    #pragma unroll
    for (int i = 0; i < 4; ++i) {
      int ob = i * 4096 + wub;
      int o_ = ob + (lane << 4);
      int r = o_ >> 7, cb = o_ & 127;
      int cbs = cb ^ ((r & 7) << 4);
      stage16((const char*)(Vt + head) + (long)r * (SS * 2) + kvbase * 2 + cbs, (char*)Vts + ob);
    }
    __syncthreads();

    f32x4 sf[4];
    #pragma unroll
    for (int nf = 0; nf < 4; ++nf) {
      f32x4 s = {0.f, 0.f, 0.f, 0.f};
      #pragma unroll
      for (int kc = 0; kc < 4; ++kc) {
        int r = nf * 16 + c;
        int ab = (r << 8) + kc * 64 + (g << 4);
        ab ^= (r & 7) << 4;
        bf16x8 kf = *(const bf16x8*)((const char*)Ks + ab);
        s = __builtin_amdgcn_mfma_f32_16x16x32_bf16(qf[kc], kf, s, 0, 0, 0);
      }
      sf[nf] = s;
    }

    if (t == qt) {
      #pragma unroll
      for (int nf = 0; nf < 4; ++nf)
        #pragma unroll
        for (int j = 0; j < 4; ++j)
          if (nf * 16 + c > w * 16 + g * 4 + j) sf[nf][j] = -INFINITY;
    }

    float mn[4], cf[4], rs[4];
    #pragma unroll
    for (int j = 0; j < 4; ++j) {
      float v = fmaxf(fmaxf(sf[0][j], sf[1][j]), fmaxf(sf[2][j], sf[3][j]));
      v = fmaxf(v, __shfl_xor(v, 1));
      v = fmaxf(v, __shfl_xor(v, 2));
      v = fmaxf(v, __shfl_xor(v, 4));
      v = fmaxf(v, __shfl_xor(v, 8));
      mn[j] = fmaxf(m[j], v);
      cf[j] = exp2f((m[j] - mn[j]) * 1.4426950408889634f);
      m[j] = mn[j];
      rs[j] = 0.f;
    }
    #pragma unroll
    for (int nf = 0; nf < 4; ++nf)
      #pragma unroll
      for (int j = 0; j < 4; ++j) {
        float p = exp2f((sf[nf][j] - mn[j]) * 1.4426950408889634f);
        sf[nf][j] = p;
        rs[j] += p;
      }
    #pragma unroll
    for (int j = 0; j < 4; ++j) {
      float v = rs[j];
      v += __shfl_xor(v, 1); v += __shfl_xor(v, 2);
      v += __shfl_xor(v, 4); v += __shfl_xor(v, 8);
      l[j] = l[j] * cf[j] + v;
    }
    #pragma unroll
    for (int nf = 0; nf < 8; ++nf)
      #pragma unroll
      for (int j = 0; j < 4; ++j)
        o[nf][j] *= cf[j];

    #pragma unroll
    for (int nf = 0; nf < 4; ++nf)
      #pragma unroll
      for (int j = 0; j < 4; ++j) {
        int pr = g * 4 + j;
        int ab = (pr << 7) + (nf * 16 + c) * 2;
        ab ^= (pr & 7) << 4;
        *(u16*)((char*)Ps[w] + ab) = f2bf(sf[nf][j]);
      }

    bf16x8 pf[2];
    #pragma unroll
    for (int kc = 0; kc < 2; ++kc) {
      int ab = (c << 7) + kc * 64 + (g << 4);
      ab ^= (c & 7) << 4;
      pf[kc] = *(const bf16x8*)((const char*)Ps[w] + ab);
    }
    #pragma unroll
    for (int nf = 0; nf < 8; ++nf) {
      #pragma unroll
      for (int kc = 0; kc < 2; ++kc) {
        int r = nf * 16 + c;
        int ab = (r << 7) + kc * 64 + (g << 4);
        ab ^= (r & 7) << 4;
        bf16x8 vf = *(const bf16x8*)((const char*)Vts + ab);
        o[nf] = __builtin_amdgcn_mfma_f32_16x16x32_bf16(pf[kc], vf, o[nf], 0, 0, 0);
      }
    }
    __syncthreads();
  }

  #pragma unroll
  for (int j = 0; j < 4; ++j) {
    float inv = 1.0f / l[j];
    int row = qbase + w * 16 + g * 4 + j;
    long ob = ((long)(b * SS + row)) * DMM + h * DHH;
    #pragma unroll
    for (int nf = 0; nf < 8; ++nf)
      Ao[ob + nf * 16 + c] = f2bf(o[nf][j] * inv);
  }
}

extern "C" void kernel_launch(void* const* d_in, const int* in_sizes, int n_in,
                              void* d_out, int out_size, void* d_ws, size_t ws_size,
                              hipStream_t stream) {
  const float* x     = (const float*)d_in[0];
  const float* w_qkv = (const float*)d_in[1];
  const float* b_qkv = (const float*)d_in[2];
  const float* w_out = (const float*)d_in[3];
  const float* b_out = (const float*)d_in[4];
  const float* fcr   = (const float*)d_in[5];
  const float* fci   = (const float*)d_in[6];
  float* outp = (float*)d_out;

  char* ws = (char*)d_ws;               // needs 96 MB
  u16* xb  = (u16*)(ws + 0);            // 16MB x bf16 [4096][2048]
  u16* wqb = (u16*)(ws + (16L << 20));  // 24MB w_qkv bf16 [6144][2048]
  u16* wob = (u16*)(ws + (40L << 20));  // 8MB  w_out bf16 [2048][2048]
  u16* Qb  = (u16*)(ws + (48L << 20));  // 16MB [bh][s][128] (scaled+roped)
  u16* Kb  = (u16*)(ws + (64L << 20));  // 16MB [bh][s][128] (roped)
  u16* Vtb = (u16*)(ws + (80L << 20));  // 16MB [bh][128][s]
  u16* attno = xb;                      // alias: xb dead after GEMM1

  cvt_bf16_k<<<4096, 256, 0, stream>>>(x, xb);
  cvt_bf16_k<<<6144, 256, 0, stream>>>(w_qkv, wqb);
  cvt_bf16_k<<<2048, 256, 0, stream>>>(w_out, wob);

  gemm_qkv8_k<<<dim3(24, 16), 512, 0, stream>>>(
      xb, wqb, b_qkv, fcr, fci, Qb, Kb, Vtb, 2048);

  attn_k<<<dim3(32, 32), 256, 0, stream>>>(Qb, Kb, Vtb, attno);

  gemm_bt_k<1><<<dim3(16, 32), 256, 0, stream>>>(
      attno, wob, b_out, outp, 2048, 2048);
}